// Round 1
// baseline (289.404 us; speedup 1.0000x reference)
//
#include <hip/hip_runtime.h>
#include <math.h>

#define B 32
#define N 512
#define DIN 768
#define DOUT 256
#define NEGV -9.0e15f
#define SLOPE 0.2f

// ---------------------------------------------------------------------------
// Kernel 1: Wh = h @ W + pos_table[positions]
// h: [B*N, DIN] row-major, W: [DIN, DOUT] row-major, Wh: [B*N, DOUT]
// Tiled fp32 GEMM: BM=64, BN=64, BK=16, 256 threads, 4x4 micro-tile.
// ---------------------------------------------------------------------------
__global__ __launch_bounds__(256) void gemm_wh(
    const float* __restrict__ A,      // h  [M=16384, K=768]
    const float* __restrict__ Wm,     // W  [768, 256]
    const int*   __restrict__ pos,    // [B*N]
    const float* __restrict__ ptab,   // [L, 256]
    float*       __restrict__ Wh)     // [M, 256]
{
    constexpr int BM = 64, BN = 64, BK = 16;
    __shared__ float As[BK][BM + 4];   // k-major, padded to keep 16B align
    __shared__ float Bs[BK][BN];

    const int t  = threadIdx.x;
    const int tx = t & 15;
    const int ty = t >> 4;
    const int m0 = blockIdx.y * BM;
    const int n0 = blockIdx.x * BN;

    const int arow = t >> 2, aq = t & 3;   // A tile: 64 rows x 4 float4
    const int brow = t >> 4, bc = t & 15;  // B tile: 16 rows x 16 float4

    float acc[4][4] = {};

    for (int k0 = 0; k0 < DIN; k0 += BK) {
        float4 av = *(const float4*)&A[(size_t)(m0 + arow) * DIN + k0 + aq * 4];
        float4 bv = *(const float4*)&Wm[(size_t)(k0 + brow) * DOUT + n0 + bc * 4];
        __syncthreads();
        As[aq * 4 + 0][arow] = av.x;
        As[aq * 4 + 1][arow] = av.y;
        As[aq * 4 + 2][arow] = av.z;
        As[aq * 4 + 3][arow] = av.w;
        *(float4*)&Bs[brow][bc * 4] = bv;
        __syncthreads();
#pragma unroll
        for (int k = 0; k < BK; ++k) {
            float4 a = *(const float4*)&As[k][ty * 4];
            float4 b = *(const float4*)&Bs[k][tx * 4];
            float af[4] = {a.x, a.y, a.z, a.w};
            float bf[4] = {b.x, b.y, b.z, b.w};
#pragma unroll
            for (int i = 0; i < 4; ++i)
#pragma unroll
                for (int j = 0; j < 4; ++j)
                    acc[i][j] += af[i] * bf[j];
        }
    }

#pragma unroll
    for (int i = 0; i < 4; ++i) {
        int gm = m0 + ty * 4 + i;
        int p  = pos[gm];
        int gn = n0 + tx * 4;
        float4 pe = *(const float4*)&ptab[(size_t)p * DOUT + gn];
        float4 o;
        o.x = acc[i][0] + pe.x;
        o.y = acc[i][1] + pe.y;
        o.z = acc[i][2] + pe.z;
        o.w = acc[i][3] + pe.w;
        *(float4*)&Wh[(size_t)gm * DOUT + gn] = o;
    }
}

// ---------------------------------------------------------------------------
// Kernel 2: s1[row] = Wh[row,:] . a1 ; s2[row] = Wh[row,:] . a2
// One block (256 threads) per row.
// ---------------------------------------------------------------------------
__global__ __launch_bounds__(256) void rowdots(
    const float* __restrict__ Wh,
    const float* __restrict__ a1,
    const float* __restrict__ a2,
    float* __restrict__ s1,
    float* __restrict__ s2)
{
    const int row = blockIdx.x;
    const int t   = threadIdx.x;
    float w  = Wh[(size_t)row * DOUT + t];
    float v1 = w * a1[t];
    float v2 = w * a2[t];
#pragma unroll
    for (int off = 32; off > 0; off >>= 1) {
        v1 += __shfl_down(v1, off);
        v2 += __shfl_down(v2, off);
    }
    __shared__ float r1[4], r2[4];
    const int wid = t >> 6;
    if ((t & 63) == 0) { r1[wid] = v1; r2[wid] = v2; }
    __syncthreads();
    if (t == 0) {
        s1[row] = r1[0] + r1[1] + r1[2] + r1[3];
        s2[row] = r2[0] + r2[1] + r2[2] + r2[3];
    }
}

// ---------------------------------------------------------------------------
// Kernel 3: attention row softmax.
// One block (256 threads) per (b,i) row; each thread handles 2 columns.
// att[b,i,j] = softmax_j( adj>0 ? leakyrelu(s1_i + s2_j) : NEG )
// ---------------------------------------------------------------------------
__global__ __launch_bounds__(256) void attn_softmax(
    const float* __restrict__ s1,
    const float* __restrict__ s2,
    const int*   __restrict__ adj,
    float*       __restrict__ att)
{
    const int row = blockIdx.x;      // b*N + i
    const int b   = row >> 9;        // N = 512
    const int t   = threadIdx.x;

    const float s1i = s1[row];
    float vals[2];
#pragma unroll
    for (int c = 0; c < 2; ++c) {
        int j = t + c * 256;
        float v = s1i + s2[b * N + j];
        v = v > 0.0f ? v : SLOPE * v;
        vals[c] = (adj[(size_t)row * N + j] > 0) ? v : NEGV;
    }

    __shared__ float red[4];
    __shared__ float bcast;

    // --- block max ---
    float m = fmaxf(vals[0], vals[1]);
#pragma unroll
    for (int off = 32; off > 0; off >>= 1)
        m = fmaxf(m, __shfl_down(m, off));
    const int wid = t >> 6;
    if ((t & 63) == 0) red[wid] = m;
    __syncthreads();
    if (t == 0) bcast = fmaxf(fmaxf(red[0], red[1]), fmaxf(red[2], red[3]));
    __syncthreads();
    m = bcast;

    // --- exp + block sum ---
    float p0 = __expf(vals[0] - m);
    float p1 = __expf(vals[1] - m);
    float s = p0 + p1;
#pragma unroll
    for (int off = 32; off > 0; off >>= 1)
        s += __shfl_down(s, off);
    __syncthreads();   // protect red[] reuse
    if ((t & 63) == 0) red[wid] = s;
    __syncthreads();
    if (t == 0) bcast = red[0] + red[1] + red[2] + red[3];
    __syncthreads();
    const float inv = 1.0f / bcast;

    att[(size_t)row * N + t]       = p0 * inv;
    att[(size_t)row * N + t + 256] = p1 * inv;
}

// ---------------------------------------------------------------------------
// Kernel 4: h_prime[b] = att[b] @ Wh[b]
// Per-batch tiled fp32 GEMM: M=512, K=512, Nout=256. Same tile scheme as k1.
// ---------------------------------------------------------------------------
__global__ __launch_bounds__(256) void gemm_hprime(
    const float* __restrict__ att,   // [B, N, N]
    const float* __restrict__ Wh,    // [B*N, DOUT]
    float*       __restrict__ hp)    // [B, N, DOUT]
{
    constexpr int BM = 64, BN = 64, BK = 16;
    __shared__ float As[BK][BM + 4];
    __shared__ float Bs[BK][BN];

    const int bb = blockIdx.z;
    const float* A  = att + (size_t)bb * N * N;       // [512, 512]
    const float* Bm = Wh  + (size_t)bb * N * DOUT;    // [512, 256]
    float*       C  = hp  + (size_t)bb * N * DOUT;

    const int t  = threadIdx.x;
    const int tx = t & 15;
    const int ty = t >> 4;
    const int m0 = blockIdx.y * BM;
    const int n0 = blockIdx.x * BN;

    const int arow = t >> 2, aq = t & 3;
    const int brow = t >> 4, bc = t & 15;

    float acc[4][4] = {};

    for (int k0 = 0; k0 < N; k0 += BK) {
        float4 av = *(const float4*)&A[(size_t)(m0 + arow) * N + k0 + aq * 4];
        float4 bv = *(const float4*)&Bm[(size_t)(k0 + brow) * DOUT + n0 + bc * 4];
        __syncthreads();
        As[aq * 4 + 0][arow] = av.x;
        As[aq * 4 + 1][arow] = av.y;
        As[aq * 4 + 2][arow] = av.z;
        As[aq * 4 + 3][arow] = av.w;
        *(float4*)&Bs[brow][bc * 4] = bv;
        __syncthreads();
#pragma unroll
        for (int k = 0; k < BK; ++k) {
            float4 a = *(const float4*)&As[k][ty * 4];
            float4 b = *(const float4*)&Bs[k][tx * 4];
            float af[4] = {a.x, a.y, a.z, a.w};
            float bf[4] = {b.x, b.y, b.z, b.w};
#pragma unroll
            for (int i = 0; i < 4; ++i)
#pragma unroll
                for (int j = 0; j < 4; ++j)
                    acc[i][j] += af[i] * bf[j];
        }
    }

#pragma unroll
    for (int i = 0; i < 4; ++i) {
        int gm = m0 + ty * 4 + i;
        int gn = n0 + tx * 4;
        float4 o = {acc[i][0], acc[i][1], acc[i][2], acc[i][3]};
        *(float4*)&C[(size_t)gm * DOUT + gn] = o;
    }
}

// ---------------------------------------------------------------------------
extern "C" void kernel_launch(void* const* d_in, const int* in_sizes, int n_in,
                              void* d_out, int out_size, void* d_ws, size_t ws_size,
                              hipStream_t stream) {
    const float* h         = (const float*)d_in[0];   // [B,N,DIN]
    const int*   adj       = (const int*)  d_in[1];   // [B,N,N]
    const int*   positions = (const int*)  d_in[2];   // [B,N]
    const float* W         = (const float*)d_in[3];   // [DIN,DOUT]
    const float* a1        = (const float*)d_in[4];   // [DOUT]
    const float* a2        = (const float*)d_in[5];   // [DOUT]
    const float* pos_table = (const float*)d_in[6];   // [L,DOUT]

    float* out      = (float*)d_out;
    float* h_prime  = out;                               // [B,N,DOUT]
    float* att      = out + (size_t)B * N * DOUT;        // [B,N,N]

    float* Wh = (float*)d_ws;                            // [B*N, DOUT]
    float* s1 = Wh + (size_t)B * N * DOUT;               // [B*N]
    float* s2 = s1 + (size_t)B * N;                      // [B*N]

    const int M = B * N;   // 16384

    // 1) Wh = h @ W + pos_emb
    {
        dim3 grid(DOUT / 64, M / 64);
        gemm_wh<<<grid, 256, 0, stream>>>(h, W, positions, pos_table, Wh);
    }
    // 2) s1, s2
    rowdots<<<M, 256, 0, stream>>>(Wh, a1, a2, s1, s2);
    // 3) attention rows (written straight into d_out)
    attn_softmax<<<M, 256, 0, stream>>>(s1, s2, adj, att);
    // 4) h_prime = att @ Wh
    {
        dim3 grid(DOUT / 64, N / 64, B);
        gemm_hprime<<<grid, 256, 0, stream>>>(att, Wh, h_prime);
    }
}

// Round 2
// 198.070 us; speedup vs baseline: 1.4611x; 1.4611x over previous
//
#include <hip/hip_runtime.h>
#include <math.h>

#define B 32
#define N 512
#define DIN 768
#define DOUT 256
#define NEGV -9.0e15f
#define SLOPE 0.2f

typedef __bf16 bf16x8 __attribute__((ext_vector_type(8)));
typedef float f32x4 __attribute__((ext_vector_type(4)));

__device__ __forceinline__ unsigned short f2b(float f) {
    union { float f; unsigned u; } v; v.f = f;
    unsigned r = v.u + 0x7FFF + ((v.u >> 16) & 1);
    return (unsigned short)(r >> 16);
}

__device__ __forceinline__ float b2f(unsigned short h) {
    union { unsigned u; float f; } v; v.u = ((unsigned)h) << 16;
    return v.f;
}

// async 16B/lane global->LDS; lds ptr must be wave-uniform (lane i lands at base+i*16)
__device__ __forceinline__ void gload_lds16(const unsigned short* g, unsigned short* l) {
    __builtin_amdgcn_global_load_lds(
        (const __attribute__((address_space(1))) unsigned int*)(unsigned long long)(uintptr_t)g,
        (__attribute__((address_space(3))) unsigned int*)(uintptr_t)l,
        16, 0, 0);
}

// ---------------------------------------------------------------------------
// convert h (fp32) -> bf16, 4 elems/thread
// ---------------------------------------------------------------------------
__global__ __launch_bounds__(256) void conv_h(const float4* __restrict__ in,
                                              ushort4* __restrict__ out) {
    int idx = blockIdx.x * 256 + threadIdx.x;
    float4 v = in[idx];
    ushort4 o;
    o.x = f2b(v.x); o.y = f2b(v.y); o.z = f2b(v.z); o.w = f2b(v.w);
    out[idx] = o;
}

// ---------------------------------------------------------------------------
// W [768][256] fp32 -> WT [256][768] bf16
// ---------------------------------------------------------------------------
__global__ __launch_bounds__(256) void conv_wt(const float* __restrict__ W,
                                               unsigned short* __restrict__ WT) {
    int k = blockIdx.x;          // 768
    int n = threadIdx.x;         // 256
    WT[(size_t)n * DIN + k] = f2b(W[(size_t)k * DOUT + n]);
}

// ---------------------------------------------------------------------------
// GEMM1: Wh = h @ W + pos_emb, output transposed bf16: WhT[b][d][j]
// A = h_bf16 [16384][768], B = WT [256][768] (n-major). 128x128 tile, BK=32.
// ---------------------------------------------------------------------------
__global__ __launch_bounds__(256) void wh_mfma(
    const unsigned short* __restrict__ hA,   // [M=16384][K=768]
    const unsigned short* __restrict__ WT,   // [256][768]
    const int*   __restrict__ pos,           // [16384]
    const float* __restrict__ ptab,          // [512][256]
    unsigned short* __restrict__ WhT)        // [32][256][512]
{
    constexpr int K = DIN;
    __shared__ unsigned short As[128 * 32];
    __shared__ unsigned short Bs[128 * 32];

    const int t    = threadIdx.x;
    const int lane = t & 63;
    const int w    = t >> 6;
    const int m0   = blockIdx.y * 128;
    const int n0   = blockIdx.x * 128;

    // staging: chunk = issue*256 + t; row=chunk>>2; lds pos p=chunk&3; global q = p ^ ((row>>1)&3)
    const int c0 = t, c1 = 256 + t;
    const int r0 = c0 >> 2, r1 = c1 >> 2;
    const int q0 = (c0 & 3) ^ ((r0 >> 1) & 3);
    const int q1 = (c1 & 3) ^ ((r1 >> 1) & 3);
    const unsigned short* gA0 = hA + (size_t)(m0 + r0) * K + q0 * 8;
    const unsigned short* gA1 = hA + (size_t)(m0 + r1) * K + q1 * 8;
    const unsigned short* gB0 = WT + (size_t)(n0 + r0) * K + q0 * 8;
    const unsigned short* gB1 = WT + (size_t)(n0 + r1) * K + q1 * 8;
    unsigned short* lA0 = As + (t & 192) * 8;
    unsigned short* lA1 = As + 2048 + (t & 192) * 8;
    unsigned short* lB0 = Bs + (t & 192) * 8;
    unsigned short* lB1 = Bs + 2048 + (t & 192) * 8;

    // fragment LDS offsets (loop-invariant, swizzled)
    const int wm = (w & 1) * 64, wn = (w >> 1) * 64;
    const int l15 = lane & 15, q = lane >> 4;
    int aoff[4], boff[4];
#pragma unroll
    for (int i = 0; i < 4; ++i) {
        int rm = wm + i * 16 + l15;
        aoff[i] = (rm * 4 + (q ^ ((rm >> 1) & 3))) * 8;
        int rn = wn + i * 16 + l15;
        boff[i] = (rn * 4 + (q ^ ((rn >> 1) & 3))) * 8;
    }

    f32x4 acc[4][4];
#pragma unroll
    for (int i = 0; i < 4; ++i)
#pragma unroll
        for (int j = 0; j < 4; ++j) acc[i][j] = (f32x4){0.f, 0.f, 0.f, 0.f};

    for (int k0 = 0; k0 < K; k0 += 32) {
        gload_lds16(gA0 + k0, lA0);
        gload_lds16(gA1 + k0, lA1);
        gload_lds16(gB0 + k0, lB0);
        gload_lds16(gB1 + k0, lB1);
        __syncthreads();
        bf16x8 af[4], bfr[4];
#pragma unroll
        for (int i = 0; i < 4; ++i) {
            af[i]  = *(const bf16x8*)(As + aoff[i]);
            bfr[i] = *(const bf16x8*)(Bs + boff[i]);
        }
#pragma unroll
        for (int mi = 0; mi < 4; ++mi)
#pragma unroll
            for (int ni = 0; ni < 4; ++ni)
                acc[mi][ni] = __builtin_amdgcn_mfma_f32_16x16x32_bf16(
                    af[mi], bfr[ni], acc[mi][ni], 0, 0, 0);
        __syncthreads();
    }

    // epilogue: add pos_emb, write WhT[b][n][j] bf16
#pragma unroll
    for (int mi = 0; mi < 4; ++mi) {
#pragma unroll
        for (int r = 0; r < 4; ++r) {
            int m = m0 + wm + mi * 16 + q * 4 + r;
            int p = pos[m];
            int bb = m >> 9, j = m & 511;
#pragma unroll
            for (int ni = 0; ni < 4; ++ni) {
                int n = n0 + wn + ni * 16 + l15;
                float val = acc[mi][ni][r] + ptab[(size_t)p * DOUT + n];
                WhT[((size_t)bb * DOUT + n) * N + j] = f2b(val);
            }
        }
    }
}

// ---------------------------------------------------------------------------
// rowdots from WhT: s1[b,j] = sum_d WhT[b][d][j]*a1[d]
// grid: 64 = b*2+half, 256 threads, coalesced over j
// ---------------------------------------------------------------------------
__global__ __launch_bounds__(256) void rowdots(
    const unsigned short* __restrict__ WhT,
    const float* __restrict__ a1, const float* __restrict__ a2,
    float* __restrict__ s1, float* __restrict__ s2)
{
    const int b = blockIdx.x >> 1, half = blockIdx.x & 1;
    const int j = half * 256 + threadIdx.x;
    __shared__ float sa1[DOUT], sa2[DOUT];
    sa1[threadIdx.x] = a1[threadIdx.x];
    sa2[threadIdx.x] = a2[threadIdx.x];
    __syncthreads();
    const unsigned short* base = WhT + (size_t)b * DOUT * N + j;
    float v1 = 0.f, v2 = 0.f;
#pragma unroll 8
    for (int d = 0; d < DOUT; ++d) {
        float wv = b2f(base[(size_t)d * N]);
        v1 += wv * sa1[d];
        v2 += wv * sa2[d];
    }
    s1[b * N + j] = v1;
    s2[b * N + j] = v2;
}

// ---------------------------------------------------------------------------
// attention softmax; writes fp32 att (output) and bf16 att (for GEMM2)
// ---------------------------------------------------------------------------
__global__ __launch_bounds__(256) void attn_softmax(
    const float* __restrict__ s1,
    const float* __restrict__ s2,
    const int*   __restrict__ adj,
    float*       __restrict__ att,
    unsigned short* __restrict__ attb)
{
    const int row = blockIdx.x;      // b*N + i
    const int b   = row >> 9;
    const int t   = threadIdx.x;

    const float s1i = s1[row];
    float vals[2];
#pragma unroll
    for (int c = 0; c < 2; ++c) {
        int j = t + c * 256;
        float v = s1i + s2[b * N + j];
        v = v > 0.0f ? v : SLOPE * v;
        vals[c] = (adj[(size_t)row * N + j] > 0) ? v : NEGV;
    }

    __shared__ float red[4];
    __shared__ float bcast;

    float m = fmaxf(vals[0], vals[1]);
#pragma unroll
    for (int off = 32; off > 0; off >>= 1)
        m = fmaxf(m, __shfl_down(m, off));
    const int wid = t >> 6;
    if ((t & 63) == 0) red[wid] = m;
    __syncthreads();
    if (t == 0) bcast = fmaxf(fmaxf(red[0], red[1]), fmaxf(red[2], red[3]));
    __syncthreads();
    m = bcast;

    float p0 = __expf(vals[0] - m);
    float p1 = __expf(vals[1] - m);
    float s = p0 + p1;
#pragma unroll
    for (int off = 32; off > 0; off >>= 1)
        s += __shfl_down(s, off);
    __syncthreads();
    if ((t & 63) == 0) red[wid] = s;
    __syncthreads();
    if (t == 0) bcast = red[0] + red[1] + red[2] + red[3];
    __syncthreads();
    const float inv = 1.0f / bcast;

    float o0 = p0 * inv, o1 = p1 * inv;
    att[(size_t)row * N + t]        = o0;
    att[(size_t)row * N + t + 256]  = o1;
    attb[(size_t)row * N + t]       = f2b(o0);
    attb[(size_t)row * N + t + 256] = f2b(o1);
}

// ---------------------------------------------------------------------------
// GEMM2: h_prime[b] = att[b] @ Wh[b]
// A = att_bf16 [512][512], B = WhT[b] [256][512] (n-major). 128x128, BK=32.
// ---------------------------------------------------------------------------
__global__ __launch_bounds__(256) void hp_mfma(
    const unsigned short* __restrict__ attb,  // [32][512][512]
    const unsigned short* __restrict__ WhT,   // [32][256][512]
    float* __restrict__ hp)                   // [32][512][256]
{
    constexpr int K = N;   // 512
    __shared__ unsigned short As[128 * 32];
    __shared__ unsigned short Bs[128 * 32];

    const int t    = threadIdx.x;
    const int lane = t & 63;
    const int w    = t >> 6;
    const int bb   = blockIdx.z;
    const int m0   = blockIdx.y * 128;
    const int n0   = blockIdx.x * 128;

    const unsigned short* A  = attb + (size_t)bb * N * N;
    const unsigned short* Bg = WhT  + (size_t)bb * DOUT * N;

    const int c0 = t, c1 = 256 + t;
    const int r0 = c0 >> 2, r1 = c1 >> 2;
    const int q0 = (c0 & 3) ^ ((r0 >> 1) & 3);
    const int q1 = (c1 & 3) ^ ((r1 >> 1) & 3);
    const unsigned short* gA0 = A  + (size_t)(m0 + r0) * K + q0 * 8;
    const unsigned short* gA1 = A  + (size_t)(m0 + r1) * K + q1 * 8;
    const unsigned short* gB0 = Bg + (size_t)(n0 + r0) * K + q0 * 8;
    const unsigned short* gB1 = Bg + (size_t)(n0 + r1) * K + q1 * 8;
    unsigned short* lA0 = As + (t & 192) * 8;
    unsigned short* lA1 = As + 2048 + (t & 192) * 8;
    unsigned short* lB0 = Bs + (t & 192) * 8;
    unsigned short* lB1 = Bs + 2048 + (t & 192) * 8;

    const int wm = (w & 1) * 64, wn = (w >> 1) * 64;
    const int l15 = lane & 15, q = lane >> 4;
    int aoff[4], boff[4];
#pragma unroll
    for (int i = 0; i < 4; ++i) {
        int rm = wm + i * 16 + l15;
        aoff[i] = (rm * 4 + (q ^ ((rm >> 1) & 3))) * 8;
        int rn = wn + i * 16 + l15;
        boff[i] = (rn * 4 + (q ^ ((rn >> 1) & 3))) * 8;
    }

    f32x4 acc[4][4];
#pragma unroll
    for (int i = 0; i < 4; ++i)
#pragma unroll
        for (int j = 0; j < 4; ++j) acc[i][j] = (f32x4){0.f, 0.f, 0.f, 0.f};

    for (int k0 = 0; k0 < K; k0 += 32) {
        gload_lds16(gA0 + k0, lA0);
        gload_lds16(gA1 + k0, lA1);
        gload_lds16(gB0 + k0, lB0);
        gload_lds16(gB1 + k0, lB1);
        __syncthreads();
        bf16x8 af[4], bfr[4];
#pragma unroll
        for (int i = 0; i < 4; ++i) {
            af[i]  = *(const bf16x8*)(As + aoff[i]);
            bfr[i] = *(const bf16x8*)(Bs + boff[i]);
        }
#pragma unroll
        for (int mi = 0; mi < 4; ++mi)
#pragma unroll
            for (int ni = 0; ni < 4; ++ni)
                acc[mi][ni] = __builtin_amdgcn_mfma_f32_16x16x32_bf16(
                    af[mi], bfr[ni], acc[mi][ni], 0, 0, 0);
        __syncthreads();
    }

#pragma unroll
    for (int mi = 0; mi < 4; ++mi) {
#pragma unroll
        for (int r = 0; r < 4; ++r) {
            int m = m0 + wm + mi * 16 + q * 4 + r;
#pragma unroll
            for (int ni = 0; ni < 4; ++ni) {
                int n = n0 + wn + ni * 16 + l15;
                hp[((size_t)bb * N + m) * DOUT + n] = acc[mi][ni][r];
            }
        }
    }
}

// ---------------------------------------------------------------------------
extern "C" void kernel_launch(void* const* d_in, const int* in_sizes, int n_in,
                              void* d_out, int out_size, void* d_ws, size_t ws_size,
                              hipStream_t stream) {
    const float* h         = (const float*)d_in[0];
    const int*   adj       = (const int*)  d_in[1];
    const int*   positions = (const int*)  d_in[2];
    const float* W         = (const float*)d_in[3];
    const float* a1        = (const float*)d_in[4];
    const float* a2        = (const float*)d_in[5];
    const float* pos_table = (const float*)d_in[6];

    float* out     = (float*)d_out;
    float* h_prime = out;                           // [B,N,DOUT]
    float* att     = out + (size_t)B * N * DOUT;    // [B,N,N]

    char* ws = (char*)d_ws;
    // layout (bytes): [0, 25165824) h_bf16, later overlaid by att_bf16 (16.8MB)
    unsigned short* h_bf  = (unsigned short*)ws;
    unsigned short* attb  = (unsigned short*)ws;                // overlay (h_bf dead)
    unsigned short* WT    = (unsigned short*)(ws + 25165824);   // 256*768*2 = 393216
    unsigned short* WhT   = (unsigned short*)(ws + 25559040);   // 32*256*512*2 = 8388608
    float*          s1    = (float*)(ws + 33947648);            // 16384*4
    float*          s2    = s1 + (size_t)B * N;

    // 1) convert h -> bf16  (12.58M elems, 4/thread)
    conv_h<<<(B * N * DIN) / 1024, 256, 0, stream>>>((const float4*)h, (ushort4*)h_bf);
    // 2) W -> WT bf16
    conv_wt<<<DIN, 256, 0, stream>>>(W, WT);
    // 3) Wh GEMM (MFMA) + pos_emb, writes WhT bf16
    {
        dim3 grid(DOUT / 128, (B * N) / 128);
        wh_mfma<<<grid, 256, 0, stream>>>(h_bf, WT, positions, pos_table, WhT);
    }
    // 4) s1,s2
    rowdots<<<B * 2, 256, 0, stream>>>(WhT, a1, a2, s1, s2);
    // 5) softmax -> att fp32 (d_out) + att bf16 (ws, overlays h_bf)
    attn_softmax<<<B * N, 256, 0, stream>>>(s1, s2, adj, att, attb);
    // 6) h_prime GEMM (MFMA)
    {
        dim3 grid(DOUT / 128, N / 128, B);
        hp_mfma<<<grid, 256, 0, stream>>>(attb, WhT, h_prime);
    }
}

// Round 4
// 182.956 us; speedup vs baseline: 1.5818x; 1.0826x over previous
//
#include <hip/hip_runtime.h>
#include <math.h>

#define B 32
#define N 512
#define DIN 768
#define DOUT 256
#define NEGV -9.0e15f
#define SLOPE 0.2f

typedef __bf16 bf16x8 __attribute__((ext_vector_type(8)));
typedef float f32x4 __attribute__((ext_vector_type(4)));
typedef unsigned short us8 __attribute__((ext_vector_type(8)));   // 16 B

__device__ __forceinline__ unsigned short f2b(float f) {
    union { float f; unsigned u; } v; v.f = f;
    unsigned r = v.u + 0x7FFF + ((v.u >> 16) & 1);
    return (unsigned short)(r >> 16);
}

__device__ __forceinline__ float b2f(unsigned short h) {
    union { unsigned u; float f; } v; v.u = ((unsigned)h) << 16;
    return v.f;
}

// async 16B/lane global->LDS; lds ptr wave-uniform (lane i lands at base+i*16)
__device__ __forceinline__ void gload_lds16(const unsigned short* g, unsigned short* l) {
    __builtin_amdgcn_global_load_lds(
        (const __attribute__((address_space(1))) unsigned int*)(unsigned long long)(uintptr_t)g,
        (__attribute__((address_space(3))) unsigned int*)(uintptr_t)l,
        16, 0, 0);
}

// ---------------------------------------------------------------------------
// convert h (fp32) -> bf16, 4 elems/thread
// ---------------------------------------------------------------------------
__global__ __launch_bounds__(256) void conv_h(const float4* __restrict__ in,
                                              ushort4* __restrict__ out) {
    int idx = blockIdx.x * 256 + threadIdx.x;
    float4 v = in[idx];
    ushort4 o;
    o.x = f2b(v.x); o.y = f2b(v.y); o.z = f2b(v.z); o.w = f2b(v.w);
    out[idx] = o;
}

// ---------------------------------------------------------------------------
// W [768][256] fp32 -> WT [256][768] bf16, LDS-transposed 64x64 tiles.
// ---------------------------------------------------------------------------
__global__ __launch_bounds__(256) void conv_wt(const float* __restrict__ W,
                                               unsigned short* __restrict__ WT) {
    __shared__ unsigned short tile[64][65];
    const int k0 = blockIdx.x * 64, n0 = blockIdx.y * 64;
    const int t = threadIdx.x;
    const int cl = t & 63, cg = t >> 6;
#pragma unroll
    for (int i = 0; i < 16; ++i) {
        int k = cg * 16 + i;
        tile[cl][k] = f2b(W[(size_t)(k0 + k) * DOUT + n0 + cl]);
    }
    __syncthreads();
#pragma unroll
    for (int i = 0; i < 16; ++i) {
        int n = cg * 16 + i;
        WT[(size_t)(n0 + n) * DIN + k0 + cl] = tile[n][cl];
    }
}

// ---------------------------------------------------------------------------
// GEMM1: Wh = h @ W + pos_emb, output WhT[b][d][j] bf16 (n-major).
// Tile 128m x 64n, BK=32, 256 thr (4 waves, each 64m x 32n).
// Epilogue transposes through LDS for coalesced WhT writes.
// ---------------------------------------------------------------------------
__global__ __launch_bounds__(256) void wh_mfma(
    const unsigned short* __restrict__ hA,   // [16384][768]
    const unsigned short* __restrict__ WT,   // [256][768]
    const int*   __restrict__ pos,           // [16384]
    const float* __restrict__ ptab,          // [512][256]
    unsigned short* __restrict__ WhT)        // [32][256][512]
{
    constexpr int K = DIN;
    __shared__ unsigned short As[128 * 32];      // 8 KB
    __shared__ unsigned short Bs[64 * 32];       // 4 KB
    __shared__ unsigned short tileT[64 * 136];   // 17.4 KB transpose buffer

    const int t    = threadIdx.x;
    const int lane = t & 63;
    const int w    = t >> 6;
    const int m0   = blockIdx.y * 128;
    const int n0   = blockIdx.x * 64;

    const int ar0 = t >> 2,          aq0 = (t & 3) ^ ((ar0 >> 1) & 3);
    const int ar1 = (256 + t) >> 2,  aq1 = (t & 3) ^ ((ar1 >> 1) & 3);
    const int br  = t >> 2,          bq  = (t & 3) ^ ((br >> 1) & 3);
    const unsigned short* gA0 = hA + (size_t)(m0 + ar0) * K + aq0 * 8;
    const unsigned short* gA1 = hA + (size_t)(m0 + ar1) * K + aq1 * 8;
    const unsigned short* gB  = WT + (size_t)(n0 + br) * K + bq * 8;
    unsigned short* lA0 = As + (t & 192) * 8;
    unsigned short* lA1 = As + 2048 + (t & 192) * 8;
    unsigned short* lB  = Bs + (t & 192) * 8;

    const int wm = (w & 1) * 64, wn = (w >> 1) * 32;
    const int l15 = lane & 15, q = lane >> 4;
    int aoff[4], boff[2];
#pragma unroll
    for (int i = 0; i < 4; ++i) {
        int rm = wm + i * 16 + l15;
        aoff[i] = (rm * 4 + (q ^ ((rm >> 1) & 3))) * 8;
    }
#pragma unroll
    for (int i = 0; i < 2; ++i) {
        int rn = wn + i * 16 + l15;
        boff[i] = (rn * 4 + (q ^ ((rn >> 1) & 3))) * 8;
    }

    f32x4 acc[4][2];
#pragma unroll
    for (int i = 0; i < 4; ++i)
#pragma unroll
        for (int j = 0; j < 2; ++j) acc[i][j] = (f32x4){0.f, 0.f, 0.f, 0.f};

    for (int k0 = 0; k0 < K; k0 += 32) {
        gload_lds16(gA0 + k0, lA0);
        gload_lds16(gA1 + k0, lA1);
        gload_lds16(gB + k0, lB);
        __syncthreads();
        bf16x8 af[4], bfr[2];
#pragma unroll
        for (int i = 0; i < 4; ++i) af[i] = *(const bf16x8*)(As + aoff[i]);
#pragma unroll
        for (int i = 0; i < 2; ++i) bfr[i] = *(const bf16x8*)(Bs + boff[i]);
#pragma unroll
        for (int mi = 0; mi < 4; ++mi)
#pragma unroll
            for (int ni = 0; ni < 2; ++ni)
                acc[mi][ni] = __builtin_amdgcn_mfma_f32_16x16x32_bf16(
                    af[mi], bfr[ni], acc[mi][ni], 0, 0, 0);
        __syncthreads();
    }

    // epilogue: + pos_emb, pack to LDS transpose tile, then coalesced write
#pragma unroll
    for (int mi = 0; mi < 4; ++mi) {
        const int jb = wm + mi * 16 + q * 4;     // local j base (r adds 0..3)
#pragma unroll
        for (int ni = 0; ni < 2; ++ni) {
            const int nl = wn + ni * 16 + l15;
            ushort4 pk;
            unsigned short* pp = (unsigned short*)&pk;
#pragma unroll
            for (int r = 0; r < 4; ++r) {
                int m = m0 + jb + r;
                int p = pos[m];
                pp[r] = f2b(acc[mi][ni][r] + ptab[(size_t)p * DOUT + n0 + nl]);
            }
            *(ushort4*)&tileT[nl * 136 + jb] = pk;
        }
    }
    __syncthreads();
    const int bb = m0 >> 9, j0 = m0 & 511;
#pragma unroll
    for (int rr = 0; rr < 4; ++rr) {
        int nl = (t >> 4) + rr * 16;
        int jl = (t & 15) * 8;                   // 8 shorts = 16 B per lane
        us8 v = *(const us8*)&tileT[nl * 136 + jl];
        *(us8*)&WhT[((size_t)bb * DOUT + n0 + nl) * N + j0 + jl] = v;
    }
}

// ---------------------------------------------------------------------------
// rowdots: s1[b,j] = sum_d WhT[b][d][j]*a1[d] (and a2).
// grid 256 = (b, jchunk of 64); threads: j_local = t&63, d-quarter = t>>6.
// ---------------------------------------------------------------------------
__global__ __launch_bounds__(256) void rowdots(
    const unsigned short* __restrict__ WhT,
    const float* __restrict__ a1, const float* __restrict__ a2,
    float* __restrict__ s1, float* __restrict__ s2)
{
    const int b = blockIdx.x >> 3, jc = blockIdx.x & 7;
    const int jl = threadIdx.x & 63, dq = threadIdx.x >> 6;
    const int j = jc * 64 + jl;
    const unsigned short* base = WhT + (size_t)b * DOUT * N + j;
    float v1 = 0.f, v2 = 0.f;
#pragma unroll 8
    for (int dd = 0; dd < 64; ++dd) {
        int d = dq * 64 + dd;
        float wv = b2f(base[(size_t)d * N]);
        v1 += wv * a1[d];
        v2 += wv * a2[d];
    }
    __shared__ float r1[4][64], r2[4][64];
    r1[dq][jl] = v1; r2[dq][jl] = v2;
    __syncthreads();
    if (dq == 0) {
        s1[b * N + j] = r1[0][jl] + r1[1][jl] + r1[2][jl] + r1[3][jl];
        s2[b * N + j] = r2[0][jl] + r2[1][jl] + r2[2][jl] + r2[3][jl];
    }
}

// ---------------------------------------------------------------------------
// attention softmax; writes fp32 att (output) and bf16 att (for GEMM2)
// ---------------------------------------------------------------------------
__global__ __launch_bounds__(256) void attn_softmax(
    const float* __restrict__ s1,
    const float* __restrict__ s2,
    const int*   __restrict__ adj,
    float*       __restrict__ att,
    unsigned short* __restrict__ attb)
{
    const int row = blockIdx.x;      // b*N + i
    const int b   = row >> 9;
    const int t   = threadIdx.x;

    const float s1i = s1[row];
    float vals[2];
#pragma unroll
    for (int c = 0; c < 2; ++c) {
        int j = t + c * 256;
        float v = s1i + s2[b * N + j];
        v = v > 0.0f ? v : SLOPE * v;
        vals[c] = (adj[(size_t)row * N + j] > 0) ? v : NEGV;
    }

    __shared__ float red[4];
    __shared__ float bcast;

    float m = fmaxf(vals[0], vals[1]);
#pragma unroll
    for (int off = 32; off > 0; off >>= 1)
        m = fmaxf(m, __shfl_down(m, off));
    const int wid = t >> 6;
    if ((t & 63) == 0) red[wid] = m;
    __syncthreads();
    if (t == 0) bcast = fmaxf(fmaxf(red[0], red[1]), fmaxf(red[2], red[3]));
    __syncthreads();
    m = bcast;

    float p0 = __expf(vals[0] - m);
    float p1 = __expf(vals[1] - m);
    float s = p0 + p1;
#pragma unroll
    for (int off = 32; off > 0; off >>= 1)
        s += __shfl_down(s, off);
    __syncthreads();
    if ((t & 63) == 0) red[wid] = s;
    __syncthreads();
    if (t == 0) bcast = red[0] + red[1] + red[2] + red[3];
    __syncthreads();
    const float inv = 1.0f / bcast;

    float o0 = p0 * inv, o1 = p1 * inv;
    att[(size_t)row * N + t]        = o0;
    att[(size_t)row * N + t + 256]  = o1;
    attb[(size_t)row * N + t]       = f2b(o0);
    attb[(size_t)row * N + t + 256] = f2b(o1);
}

// ---------------------------------------------------------------------------
// GEMM2: h_prime[b] = att[b] @ Wh[b].  A = attb [512][512], B = WhT[b]
// [256][512] n-major. Tile 128m x 64n, BK=32, grid (4,4,32) = 512 blocks.
// ---------------------------------------------------------------------------
__global__ __launch_bounds__(256) void hp_mfma(
    const unsigned short* __restrict__ attb,  // [32][512][512]
    const unsigned short* __restrict__ WhT,   // [32][256][512]
    float* __restrict__ hp)                   // [32][512][256]
{
    constexpr int K = N;
    __shared__ unsigned short As[128 * 32];
    __shared__ unsigned short Bs[64 * 32];

    const int t    = threadIdx.x;
    const int lane = t & 63;
    const int w    = t >> 6;
    const int bb   = blockIdx.z;
    const int m0   = blockIdx.y * 128;
    const int n0   = blockIdx.x * 64;

    const unsigned short* A  = attb + (size_t)bb * N * N;
    const unsigned short* Bg = WhT  + (size_t)bb * DOUT * N;

    const int ar0 = t >> 2,          aq0 = (t & 3) ^ ((ar0 >> 1) & 3);
    const int ar1 = (256 + t) >> 2,  aq1 = (t & 3) ^ ((ar1 >> 1) & 3);
    const int br  = t >> 2,          bq  = (t & 3) ^ ((br >> 1) & 3);
    const unsigned short* gA0 = A  + (size_t)(m0 + ar0) * K + aq0 * 8;
    const unsigned short* gA1 = A  + (size_t)(m0 + ar1) * K + aq1 * 8;
    const unsigned short* gB  = Bg + (size_t)(n0 + br) * K + bq * 8;
    unsigned short* lA0 = As + (t & 192) * 8;
    unsigned short* lA1 = As + 2048 + (t & 192) * 8;
    unsigned short* lB  = Bs + (t & 192) * 8;

    const int wm = (w & 1) * 64, wn = (w >> 1) * 32;
    const int l15 = lane & 15, q = lane >> 4;
    int aoff[4], boff[2];
#pragma unroll
    for (int i = 0; i < 4; ++i) {
        int rm = wm + i * 16 + l15;
        aoff[i] = (rm * 4 + (q ^ ((rm >> 1) & 3))) * 8;
    }
#pragma unroll
    for (int i = 0; i < 2; ++i) {
        int rn = wn + i * 16 + l15;
        boff[i] = (rn * 4 + (q ^ ((rn >> 1) & 3))) * 8;
    }

    f32x4 acc[4][2];
#pragma unroll
    for (int i = 0; i < 4; ++i)
#pragma unroll
        for (int j = 0; j < 2; ++j) acc[i][j] = (f32x4){0.f, 0.f, 0.f, 0.f};

    for (int k0 = 0; k0 < K; k0 += 32) {
        gload_lds16(gA0 + k0, lA0);
        gload_lds16(gA1 + k0, lA1);
        gload_lds16(gB + k0, lB);
        __syncthreads();
        bf16x8 af[4], bfr[2];
#pragma unroll
        for (int i = 0; i < 4; ++i) af[i] = *(const bf16x8*)(As + aoff[i]);
#pragma unroll
        for (int i = 0; i < 2; ++i) bfr[i] = *(const bf16x8*)(Bs + boff[i]);
#pragma unroll
        for (int mi = 0; mi < 4; ++mi)
#pragma unroll
            for (int ni = 0; ni < 2; ++ni)
                acc[mi][ni] = __builtin_amdgcn_mfma_f32_16x16x32_bf16(
                    af[mi], bfr[ni], acc[mi][ni], 0, 0, 0);
        __syncthreads();
    }

#pragma unroll
    for (int mi = 0; mi < 4; ++mi) {
#pragma unroll
        for (int r = 0; r < 4; ++r) {
            int m = m0 + wm + mi * 16 + q * 4 + r;
#pragma unroll
            for (int ni = 0; ni < 2; ++ni) {
                int n = n0 + wn + ni * 16 + l15;
                hp[((size_t)bb * N + m) * DOUT + n] = acc[mi][ni][r];
            }
        }
    }
}

// ---------------------------------------------------------------------------
extern "C" void kernel_launch(void* const* d_in, const int* in_sizes, int n_in,
                              void* d_out, int out_size, void* d_ws, size_t ws_size,
                              hipStream_t stream) {
    const float* h         = (const float*)d_in[0];
    const int*   adj       = (const int*)  d_in[1];
    const int*   positions = (const int*)  d_in[2];
    const float* W         = (const float*)d_in[3];
    const float* a1        = (const float*)d_in[4];
    const float* a2        = (const float*)d_in[5];
    const float* pos_table = (const float*)d_in[6];

    float* out     = (float*)d_out;
    float* h_prime = out;                           // [B,N,DOUT]
    float* att     = out + (size_t)B * N * DOUT;    // [B,N,N]

    char* ws = (char*)d_ws;
    unsigned short* h_bf  = (unsigned short*)ws;                // 25.2 MB
    unsigned short* attb  = (unsigned short*)ws;                // overlay (h_bf dead)
    unsigned short* WT    = (unsigned short*)(ws + 25165824);   // 0.39 MB
    unsigned short* WhT   = (unsigned short*)(ws + 25559040);   // 8.39 MB
    float*          s1    = (float*)(ws + 33947648);
    float*          s2    = s1 + (size_t)B * N;

    // 1) h -> bf16
    conv_h<<<(B * N * DIN) / 1024, 256, 0, stream>>>((const float4*)h, (ushort4*)h_bf);
    // 2) W -> WT bf16 (LDS transpose)
    {
        dim3 grid(DIN / 64, DOUT / 64);
        conv_wt<<<grid, 256, 0, stream>>>(W, WT);
    }
    // 3) Wh GEMM + pos_emb -> WhT bf16 (512 blocks = 2/CU)
    {
        dim3 grid(DOUT / 64, (B * N) / 128);
        wh_mfma<<<grid, 256, 0, stream>>>(h_bf, WT, positions, pos_table, WhT);
    }
    // 4) s1,s2 (256 blocks)
    rowdots<<<B * 8, 256, 0, stream>>>(WhT, a1, a2, s1, s2);
    // 5) softmax -> att fp32 + att bf16
    attn_softmax<<<B * N, 256, 0, stream>>>(s1, s2, adj, att, attb);
    // 6) h_prime GEMM (512 blocks = 2/CU)
    {
        dim3 grid(DOUT / 64, N / 128, B);
        hp_mfma<<<grid, 256, 0, stream>>>(attb, WhT, h_prime);
    }
}

// Round 5
// 171.960 us; speedup vs baseline: 1.6830x; 1.0639x over previous
//
#include <hip/hip_runtime.h>
#include <math.h>

#define B 32
#define N 512
#define DIN 768
#define DOUT 256
#define NEGV -9.0e15f
#define SLOPE 0.2f

typedef __bf16 bf16x8 __attribute__((ext_vector_type(8)));
typedef float f32x4 __attribute__((ext_vector_type(4)));
typedef unsigned short us8 __attribute__((ext_vector_type(8)));   // 16 B

__device__ __forceinline__ unsigned short f2b(float f) {
    union { float f; unsigned u; } v; v.f = f;
    unsigned r = v.u + 0x7FFF + ((v.u >> 16) & 1);
    return (unsigned short)(r >> 16);
}

__device__ __forceinline__ float b2f(unsigned short h) {
    union { unsigned u; float f; } v; v.u = ((unsigned)h) << 16;
    return v.f;
}

// async 16B/lane global->LDS; lds ptr wave-uniform (lane i lands at base+i*16)
__device__ __forceinline__ void gload_lds16(const unsigned short* g, unsigned short* l) {
    __builtin_amdgcn_global_load_lds(
        (const __attribute__((address_space(1))) unsigned int*)(unsigned long long)(uintptr_t)g,
        (__attribute__((address_space(3))) unsigned int*)(uintptr_t)l,
        16, 0, 0);
}

// ---------------------------------------------------------------------------
// fused: blocks [0,12288) convert h fp32->bf16 (4/thr);
//        blocks [12288,12336) transpose W -> WT bf16 (64x64 LDS tiles)
// ---------------------------------------------------------------------------
__global__ __launch_bounds__(256) void conv_fused(
    const float4* __restrict__ hin, ushort4* __restrict__ hout,
    const float* __restrict__ W, unsigned short* __restrict__ WT) {
    __shared__ unsigned short tile[64][65];
    const int t = threadIdx.x;
    if (blockIdx.x < 12288) {
        int idx = blockIdx.x * 256 + t;
        float4 v = hin[idx];
        ushort4 o;
        o.x = f2b(v.x); o.y = f2b(v.y); o.z = f2b(v.z); o.w = f2b(v.w);
        hout[idx] = o;
    } else {
        int bid = blockIdx.x - 12288;
        int k0 = (bid % 12) * 64, n0 = (bid / 12) * 64;
        const int cl = t & 63, cg = t >> 6;
#pragma unroll
        for (int i = 0; i < 16; ++i) {
            int k = cg * 16 + i;
            tile[cl][k] = f2b(W[(size_t)(k0 + k) * DOUT + n0 + cl]);
        }
        __syncthreads();
#pragma unroll
        for (int i = 0; i < 16; ++i) {
            int n = cg * 16 + i;
            WT[(size_t)(n0 + n) * DIN + k0 + cl] = tile[n][cl];
        }
    }
}

// ---------------------------------------------------------------------------
// GEMM1: Wh = h @ W + pos_emb -> WhT[b][d][j] bf16 (n-major), fused s1/s2.
// Tile 128m x 64n, BK=64, 256 thr (4 waves, each 64m x 32n).
// 1-D grid 512: m-tile = lin&127, n-tile = lin>>7 (same-m group shares XCD).
// ---------------------------------------------------------------------------
__global__ __launch_bounds__(256) void wh_mfma(
    const unsigned short* __restrict__ hA,   // [16384][768]
    const unsigned short* __restrict__ WT,   // [256][768]
    const int*   __restrict__ pos,           // [16384]
    const float* __restrict__ ptab,          // [512][256]
    const float* __restrict__ a1,
    const float* __restrict__ a2,
    unsigned short* __restrict__ WhT,        // [32][256][512]
    float* __restrict__ s1, float* __restrict__ s2)
{
    constexpr int K = DIN;
    // As: 128 rows x 64k = 8192 shorts; Bs: 64 x 64 = 4096; tileT overlays (8704)
    __shared__ unsigned short smem[12288];
    unsigned short* As = smem;
    unsigned short* Bs = smem + 8192;
    unsigned short* tileT = smem;            // reused after k-loop

    const int t    = threadIdx.x;
    const int lane = t & 63;
    const int w    = t >> 6;
    const int lin  = blockIdx.x;
    const int m0   = (lin & 127) * 128;
    const int n0   = (lin >> 7) * 64;

    // staging chunk maps: chunk c -> row r = c>>3, lds slot s = c&7, global pos pg = s^(r&7)
    int arow[4], apos[4];
#pragma unroll
    for (int i = 0; i < 4; ++i) {
        int c = i * 256 + t;
        arow[i] = c >> 3;
        apos[i] = (c & 7) ^ ((c >> 3) & 7);
    }
    int brow[2], bpos[2];
#pragma unroll
    for (int i = 0; i < 2; ++i) {
        int c = i * 256 + t;
        brow[i] = c >> 3;
        bpos[i] = (c & 7) ^ ((c >> 3) & 7);
    }
    const unsigned short* gA[4];
    const unsigned short* gB[2];
#pragma unroll
    for (int i = 0; i < 4; ++i) gA[i] = hA + (size_t)(m0 + arow[i]) * K + apos[i] * 8;
#pragma unroll
    for (int i = 0; i < 2; ++i) gB[i] = WT + (size_t)(n0 + brow[i]) * K + bpos[i] * 8;
    unsigned short* lA[4];
    unsigned short* lB[2];
#pragma unroll
    for (int i = 0; i < 4; ++i) lA[i] = As + (i * 256 + (t & 192)) * 8;
#pragma unroll
    for (int i = 0; i < 2; ++i) lB[i] = Bs + (i * 256 + (t & 192)) * 8;

    const int wm = (w & 1) * 64, wn = (w >> 1) * 32;
    const int l15 = lane & 15, q = lane >> 4;
    // fragment offsets: row stride 64 shorts; slot s = (kk/8 + q) ^ (row&7)
    int aoff[2][4], boff[2][2];
#pragma unroll
    for (int kk = 0; kk < 2; ++kk) {
        int pg = kk * 4 + q;
#pragma unroll
        for (int i = 0; i < 4; ++i) {
            int rm = wm + i * 16 + l15;
            aoff[kk][i] = rm * 64 + ((pg ^ (rm & 7)) * 8);
        }
#pragma unroll
        for (int i = 0; i < 2; ++i) {
            int rn = wn + i * 16 + l15;
            boff[kk][i] = rn * 64 + ((pg ^ (rn & 7)) * 8);
        }
    }

    f32x4 acc[4][2];
#pragma unroll
    for (int i = 0; i < 4; ++i)
#pragma unroll
        for (int j = 0; j < 2; ++j) acc[i][j] = (f32x4){0.f, 0.f, 0.f, 0.f};

    for (int k0 = 0; k0 < K; k0 += 64) {
#pragma unroll
        for (int i = 0; i < 4; ++i) gload_lds16(gA[i] + k0, lA[i]);
#pragma unroll
        for (int i = 0; i < 2; ++i) gload_lds16(gB[i] + k0, lB[i]);
        __syncthreads();
#pragma unroll
        for (int kk = 0; kk < 2; ++kk) {
            bf16x8 af[4], bfr[2];
#pragma unroll
            for (int i = 0; i < 4; ++i) af[i] = *(const bf16x8*)(As + aoff[kk][i]);
#pragma unroll
            for (int i = 0; i < 2; ++i) bfr[i] = *(const bf16x8*)(Bs + boff[kk][i]);
#pragma unroll
            for (int mi = 0; mi < 4; ++mi)
#pragma unroll
                for (int ni = 0; ni < 2; ++ni)
                    acc[mi][ni] = __builtin_amdgcn_mfma_f32_16x16x32_bf16(
                        af[mi], bfr[ni], acc[mi][ni], 0, 0, 0);
        }
        __syncthreads();
    }

    // epilogue: + pos_emb; fused s1/s2 partials; transpose tile; coalesced write
    const float a1v[2] = { a1[n0 + wn + l15], a1[n0 + wn + 16 + l15] };
    const float a2v[2] = { a2[n0 + wn + l15], a2[n0 + wn + 16 + l15] };
#pragma unroll
    for (int mi = 0; mi < 4; ++mi) {
        const int jb = wm + mi * 16 + q * 4;
        float v[2][4];
#pragma unroll
        for (int ni = 0; ni < 2; ++ni) {
            const int nl = wn + ni * 16 + l15;
            ushort4 pk;
            unsigned short* pp = (unsigned short*)&pk;
#pragma unroll
            for (int r = 0; r < 4; ++r) {
                int m = m0 + jb + r;
                int p = pos[m];
                float val = acc[mi][ni][r] + ptab[(size_t)p * DOUT + n0 + nl];
                v[ni][r] = val;
                pp[r] = f2b(val);
            }
            *(ushort4*)&tileT[nl * 136 + jb] = pk;
        }
        // s1/s2 partials over this wave's 32-wide n slice
#pragma unroll
        for (int r = 0; r < 4; ++r) {
            float t1 = v[0][r] * a1v[0] + v[1][r] * a1v[1];
            float t2 = v[0][r] * a2v[0] + v[1][r] * a2v[1];
#pragma unroll
            for (int mk = 1; mk < 16; mk <<= 1) {
                t1 += __shfl_xor(t1, mk);
                t2 += __shfl_xor(t2, mk);
            }
            if (l15 == 0) {
                atomicAdd(&s1[m0 + jb + r], t1);
                atomicAdd(&s2[m0 + jb + r], t2);
            }
        }
    }
    __syncthreads();
    const int bb = m0 >> 9, j0 = m0 & 511;
#pragma unroll
    for (int rr = 0; rr < 4; ++rr) {
        int nl = (t >> 4) + rr * 16;
        int jl = (t & 15) * 8;
        us8 vv = *(const us8*)&tileT[nl * 136 + jl];
        *(us8*)&WhT[((size_t)bb * DOUT + n0 + nl) * N + j0 + jl] = vv;
    }
}

// ---------------------------------------------------------------------------
// attention softmax; 2 contiguous j per thread; fp32 att + packed bf16 att
// ---------------------------------------------------------------------------
__global__ __launch_bounds__(256) void attn_softmax(
    const float* __restrict__ s1,
    const float* __restrict__ s2,
    const int*   __restrict__ adj,
    float*       __restrict__ att,
    unsigned int* __restrict__ attb)   // packed 2x bf16
{
    const int row = blockIdx.x;      // b*N + i
    const int b   = row >> 9;
    const int t   = threadIdx.x;

    const float s1i = s1[row];
    const float2 s2p = ((const float2*)(s2 + b * N))[t];
    const int2   ap  = ((const int2*)(adj + (size_t)row * N))[t];

    float v0 = s1i + s2p.x; v0 = v0 > 0.f ? v0 : SLOPE * v0;
    float v1 = s1i + s2p.y; v1 = v1 > 0.f ? v1 : SLOPE * v1;
    v0 = (ap.x > 0) ? v0 : NEGV;
    v1 = (ap.y > 0) ? v1 : NEGV;

    __shared__ float red[4];
    __shared__ float bcast;

    float m = fmaxf(v0, v1);
#pragma unroll
    for (int off = 32; off > 0; off >>= 1)
        m = fmaxf(m, __shfl_down(m, off));
    const int wid = t >> 6;
    if ((t & 63) == 0) red[wid] = m;
    __syncthreads();
    if (t == 0) bcast = fmaxf(fmaxf(red[0], red[1]), fmaxf(red[2], red[3]));
    __syncthreads();
    m = bcast;

    float p0 = __expf(v0 - m);
    float p1 = __expf(v1 - m);
    float s = p0 + p1;
#pragma unroll
    for (int off = 32; off > 0; off >>= 1)
        s += __shfl_down(s, off);
    __syncthreads();
    if ((t & 63) == 0) red[wid] = s;
    __syncthreads();
    if (t == 0) bcast = red[0] + red[1] + red[2] + red[3];
    __syncthreads();
    const float inv = 1.0f / bcast;

    float o0 = p0 * inv, o1 = p1 * inv;
    ((float2*)(att + (size_t)row * N))[t] = (float2){o0, o1};
    attb[(size_t)row * 256 + t] = (unsigned)f2b(o0) | ((unsigned)f2b(o1) << 16);
}

// ---------------------------------------------------------------------------
// GEMM2: h_prime[b] = att[b] @ Wh[b].  A = attb [512][512] bf16, B = WhT[b]
// [256][512] n-major. Tile 128m x 64n, BK=64.
// 1-D grid 512: n-tile = lin>>7; (bb,mt) = lin&127 (same-A group shares XCD).
// ---------------------------------------------------------------------------
__global__ __launch_bounds__(256) void hp_mfma(
    const unsigned short* __restrict__ attb,  // [32][512][512]
    const unsigned short* __restrict__ WhT,   // [32][256][512]
    float* __restrict__ hp)                   // [32][512][256]
{
    constexpr int K = N;
    __shared__ unsigned short smem[12288];
    unsigned short* As = smem;
    unsigned short* Bs = smem + 8192;

    const int t    = threadIdx.x;
    const int lane = t & 63;
    const int w    = t >> 6;
    const int lin  = blockIdx.x;
    const int n0   = (lin >> 7) * 64;
    const int rest = lin & 127;
    const int bb   = rest >> 2;
    const int m0   = (rest & 3) * 128;

    const unsigned short* A  = attb + (size_t)bb * N * N;
    const unsigned short* Bg = WhT  + (size_t)bb * DOUT * N;

    int arow[4], apos[4];
#pragma unroll
    for (int i = 0; i < 4; ++i) {
        int c = i * 256 + t;
        arow[i] = c >> 3;
        apos[i] = (c & 7) ^ ((c >> 3) & 7);
    }
    int brow[2], bpos[2];
#pragma unroll
    for (int i = 0; i < 2; ++i) {
        int c = i * 256 + t;
        brow[i] = c >> 3;
        bpos[i] = (c & 7) ^ ((c >> 3) & 7);
    }
    const unsigned short* gA[4];
    const unsigned short* gB[2];
#pragma unroll
    for (int i = 0; i < 4; ++i) gA[i] = A + (size_t)(m0 + arow[i]) * K + apos[i] * 8;
#pragma unroll
    for (int i = 0; i < 2; ++i) gB[i] = Bg + (size_t)(n0 + brow[i]) * K + bpos[i] * 8;
    unsigned short* lA[4];
    unsigned short* lB[2];
#pragma unroll
    for (int i = 0; i < 4; ++i) lA[i] = As + (i * 256 + (t & 192)) * 8;
#pragma unroll
    for (int i = 0; i < 2; ++i) lB[i] = Bs + (i * 256 + (t & 192)) * 8;

    const int wm = (w & 1) * 64, wn = (w >> 1) * 32;
    const int l15 = lane & 15, q = lane >> 4;
    int aoff[2][4], boff[2][2];
#pragma unroll
    for (int kk = 0; kk < 2; ++kk) {
        int pg = kk * 4 + q;
#pragma unroll
        for (int i = 0; i < 4; ++i) {
            int rm = wm + i * 16 + l15;
            aoff[kk][i] = rm * 64 + ((pg ^ (rm & 7)) * 8);
        }
#pragma unroll
        for (int i = 0; i < 2; ++i) {
            int rn = wn + i * 16 + l15;
            boff[kk][i] = rn * 64 + ((pg ^ (rn & 7)) * 8);
        }
    }

    f32x4 acc[4][2];
#pragma unroll
    for (int i = 0; i < 4; ++i)
#pragma unroll
        for (int j = 0; j < 2; ++j) acc[i][j] = (f32x4){0.f, 0.f, 0.f, 0.f};

    for (int k0 = 0; k0 < K; k0 += 64) {
#pragma unroll
        for (int i = 0; i < 4; ++i) gload_lds16(gA[i] + k0, lA[i]);
#pragma unroll
        for (int i = 0; i < 2; ++i) gload_lds16(gB[i] + k0, lB[i]);
        __syncthreads();
#pragma unroll
        for (int kk = 0; kk < 2; ++kk) {
            bf16x8 af[4], bfr[2];
#pragma unroll
            for (int i = 0; i < 4; ++i) af[i] = *(const bf16x8*)(As + aoff[kk][i]);
#pragma unroll
            for (int i = 0; i < 2; ++i) bfr[i] = *(const bf16x8*)(Bs + boff[kk][i]);
#pragma unroll
            for (int mi = 0; mi < 4; ++mi)
#pragma unroll
                for (int ni = 0; ni < 2; ++ni)
                    acc[mi][ni] = __builtin_amdgcn_mfma_f32_16x16x32_bf16(
                        af[mi], bfr[ni], acc[mi][ni], 0, 0, 0);
        }
        __syncthreads();
    }

#pragma unroll
    for (int mi = 0; mi < 4; ++mi) {
#pragma unroll
        for (int r = 0; r < 4; ++r) {
            int m = m0 + wm + mi * 16 + q * 4 + r;
#pragma unroll
            for (int ni = 0; ni < 2; ++ni) {
                int n = n0 + wn + ni * 16 + l15;
                hp[((size_t)bb * N + m) * DOUT + n] = acc[mi][ni][r];
            }
        }
    }
}

// ---------------------------------------------------------------------------
extern "C" void kernel_launch(void* const* d_in, const int* in_sizes, int n_in,
                              void* d_out, int out_size, void* d_ws, size_t ws_size,
                              hipStream_t stream) {
    const float* h         = (const float*)d_in[0];
    const int*   adj       = (const int*)  d_in[1];
    const int*   positions = (const int*)  d_in[2];
    const float* W         = (const float*)d_in[3];
    const float* a1        = (const float*)d_in[4];
    const float* a2        = (const float*)d_in[5];
    const float* pos_table = (const float*)d_in[6];

    float* out     = (float*)d_out;
    float* h_prime = out;                           // [B,N,DOUT]
    float* att     = out + (size_t)B * N * DOUT;    // [B,N,N]

    char* ws = (char*)d_ws;
    unsigned short* h_bf  = (unsigned short*)ws;                // 25.2 MB
    unsigned short* attb  = (unsigned short*)ws;                // overlay (h_bf dead)
    unsigned short* WT    = (unsigned short*)(ws + 25165824);   // 0.39 MB
    unsigned short* WhT   = (unsigned short*)(ws + 25559040);   // 8.39 MB
    float*          s1    = (float*)(ws + 33947648);            // 64 KB
    float*          s2    = s1 + (size_t)B * N;

    // 0) zero s1/s2 for the fused atomics
    hipMemsetAsync(s1, 0, (size_t)2 * B * N * sizeof(float), stream);
    // 1) h -> bf16 and W -> WT bf16 (one launch)
    conv_fused<<<12288 + 48, 256, 0, stream>>>((const float4*)h, (ushort4*)h_bf, W, WT);
    // 2) Wh GEMM + pos_emb -> WhT bf16, fused s1/s2 (512 blocks, XCD-swizzled)
    wh_mfma<<<512, 256, 0, stream>>>(h_bf, WT, positions, pos_table, a1, a2, WhT, s1, s2);
    // 3) softmax -> att fp32 + att bf16
    attn_softmax<<<B * N, 256, 0, stream>>>(s1, s2, adj, att, (unsigned int*)attb);
    // 4) h_prime GEMM (512 blocks, XCD-swizzled)
    hp_mfma<<<512, 256, 0, stream>>>(attb, WhT, h_prime);
}